// Round 5
// baseline (337.181 us; speedup 1.0000x reference)
//
#include <hip/hip_runtime.h>

// GymNetwork: routed MLP, B=262144, D=128 -> F=80 -> 80 -> 80 -> A=18, G=8 (idx sorted).
// f32 I/O, bf16 MFMA compute (threshold 6e-2 = 8*bf16_eps*max|ref|).
//
// R15: R14's WRITE_SIZE stayed at 284MB with ZERO register arrays -> the scratch is
// register-pressure spill against the launch_bounds(512,4) cap of 128 total regs
// (arch+accum share the gfx950 unified file), NOT array demotion. Dominant cause: the
// 8 state fragments (32 VGPRs) were hoisted ABOVE the g-loop, staying live across
// L1+L2+L3+L4. Fix: load+convert state INSIDE the g-loop so af dies after L1
// (g-loop runs once per slab except at rare game boundaries; reloads there are L2-hot).
// Peak live: L1 ~75, L2/L3 ~60 -> fits 128 with slack. Everything else = R14.

#define B_TOT   262144
#define DDIM    128
#define FDIM    80
#define ADIM    18
#define SH      104    // LDS stride (shorts) for h rows; 208B breaks pow2 bank stride
#define THREADS 512
#define SLAB    256    // rows per block-iteration (8 waves x 32)
#define NSLAB   2      // block rows = 512
#define GRID    (B_TOT / (SLAB * NSLAB))   // 512 blocks = 2/CU

// swizzled bf16 weight workspace in d_ws (shorts); 512-short (1KB) chunks, lane-major
#define W1SW    0                       // 200 chunks: (g*25 + ks*5 + ct); ks=4 = b1 col
#define W2SW    102400                  // 15 chunks: (ks*5+ct); k=80 holds b2, 81..95 zero
#define W3SW    110080                  // 15 chunks; k=80 holds b3
#define W4SW    117760                  // 48 chunks: (g*6+ks*2+ct); k=80 holds b4
#define NCHUNK  278
#define WTOT    (NCHUNK * 512)          // 142336 shorts = 284672 bytes

// LDS layout (shorts)
#define LW1     0                       // 25 chunks (current g) = 12800
#define LHB     12800                   // 8 waves x 32 x SH = 26624
#define LDS_SH  39424                   // 78848 B -> 2 blocks/CU

typedef __attribute__((ext_vector_type(8))) short short8;
typedef __attribute__((ext_vector_type(2))) unsigned int uint2v;
typedef __attribute__((ext_vector_type(4))) float floatx4;
typedef __attribute__((ext_vector_type(2))) float floatx2;

static __device__ __forceinline__ unsigned short f2bf(float f) {
  union { float f; unsigned u; } v; v.f = f;
  unsigned r = v.u + 0x7fffu + ((v.u >> 16) & 1u);   // RNE
  return (unsigned short)(r >> 16);
}
// pack two f32 -> bf16x2 (lo | hi<<16), RNE
static __device__ __forceinline__ unsigned pk2(float a, float b) {
  union { float f; unsigned u; } x, y; x.f = a; y.f = b;
  unsigned ra = x.u + 0x7fffu + ((x.u >> 16) & 1u);
  unsigned rb = y.u + 0x7fffu + ((y.u >> 16) & 1u);
  return (ra >> 16) | (rb & 0xffff0000u);
}
// load 8 consecutive f32 -> one bf16x8 fragment (named-scalar friendly)
static __device__ __forceinline__ short8 ldbf8(const float* sp) {
  floatx4 va = *(const floatx4*)(sp);
  floatx4 vb = *(const floatx4*)(sp + 4);
  short8 f;
  unsigned u0 = pk2(va[0], va[1]), u1 = pk2(va[2], va[3]);
  unsigned u2 = pk2(vb[0], vb[1]), u3 = pk2(vb[2], vb[3]);
  f[0] = (short)(u0 & 0xffff); f[1] = (short)(u0 >> 16);
  f[2] = (short)(u1 & 0xffff); f[3] = (short)(u1 >> 16);
  f[4] = (short)(u2 & 0xffff); f[5] = (short)(u2 >> 16);
  f[6] = (short)(u3 & 0xffff); f[7] = (short)(u3 >> 16);
  return f;
}

// ---- prologue: f32 weights -> bf16 swizzled chunks; biases folded into extra-k cols ----
// chunk: ws[chunk*512 + lane*8 + j] = W[n = ct*16 + (lane&15)][k = ks*32 + (lane>>4)*8 + j]
__global__ void convert_weights(const float* __restrict__ W1, const float* __restrict__ b1,
                                const float* __restrict__ W2, const float* __restrict__ W3,
                                const float* __restrict__ W4, const float* __restrict__ b2,
                                const float* __restrict__ b3, const float* __restrict__ b4,
                                unsigned short* __restrict__ ws) {
  int t = blockIdx.x * 256 + threadIdx.x;
  if (t >= WTOT) return;
  int chunk = t >> 9, r = t & 511;
  int lane = r >> 3, j = r & 7;
  int l16 = lane & 15, quad = lane >> 4;
  float val;
  if (chunk < 200) {                              // W1: [G][80][128] + ks=4 bias col
    int g = chunk / 25, rem = chunk % 25, ks = rem / 5, ct = rem % 5;
    int n = ct * 16 + l16, k = ks * 32 + quad * 8 + j;
    val = (ks < 4) ? W1[(g * FDIM + n) * DDIM + k]
                   : ((quad == 0 && j == 0) ? b1[g * FDIM + n] : 0.f);
  } else if (chunk < 215) {                       // W2: 80x80 -> 80x96, k80 = b2[n]
    int c = chunk - 200, ks = c / 5, ct = c % 5;
    int n = ct * 16 + l16, k = ks * 32 + quad * 8 + j;
    val = (k < FDIM) ? W2[n * FDIM + k] : (k == FDIM ? b2[n] : 0.f);
  } else if (chunk < 230) {                       // W3, k80 = b3[n]
    int c = chunk - 215, ks = c / 5, ct = c % 5;
    int n = ct * 16 + l16, k = ks * 32 + quad * 8 + j;
    val = (k < FDIM) ? W3[n * FDIM + k] : (k == FDIM ? b3[n] : 0.f);
  } else {                                        // W4: Gx18x80 -> Gx32x96, k80 = b4[g][n]
    int c = chunk - 230, g = c / 6, rem = c % 6, ks = rem >> 1, ct = rem & 1;
    int n = ct * 16 + l16, k = ks * 32 + quad * 8 + j;
    val = (n < ADIM) ? ((k < FDIM) ? W4[(g * ADIM + n) * FDIM + k]
                                   : (k == FDIM ? b4[g * ADIM + n] : 0.f)) : 0.f;
  }
  ws[t] = f2bf(val);
}

// W1[g] (25 chunks incl. bias col) -> LDS; barrier pair; block-uniform call sites
static __device__ __forceinline__ void stage_game(
    int g, const unsigned short* __restrict__ wsw, unsigned short* smem, int tid)
{
  __syncthreads();                                // all waves done with old W1
  const short8* src = (const short8*)(wsw + W1SW + g * (25 * 512));
  short8* dst = (short8*)(smem + LW1);
#pragma unroll
  for (int i = 0; i < 4; ++i) {
    int t = i * THREADS + tid;
    if (t < 1600) dst[t] = src[t];
  }
  __syncthreads();                                // new W1 visible
}

#define Z4 ((floatx4){0.f, 0.f, 0.f, 0.f})
#define MFMA(a, b, c) __builtin_amdgcn_mfma_f32_16x16x32_bf16((a), (b), (c), 0, 0, 0)

// relu + pack + h-store of one ct's 4-float acc (row ROW of this wave's hbuf)
#define H_STORE(ROW, CT, ACC) {                                            \
    uint2v u_;                                                             \
    u_[0] = pk2(fmaxf((ACC)[0], 0.f), fmaxf((ACC)[1], 0.f));               \
    u_[1] = pk2(fmaxf((ACC)[2], 0.f), fmaxf((ACC)[3], 0.f));               \
    *(uint2v*)(hbuf + (ROW) * SH + (CT) * 16 + quad * 4) = u_;             \
  }

// ---- L1: W1 from LDS; hand-unrolled ks steps over NAMED b-frags ----
#define L1_STEP(KS, CT0, CT1, BA, BB) {                                    \
    short8 wf0 = *(const short8*)(smem + LW1 + ((KS) * 5 + (CT0)) * 512 + lane * 8); \
    short8 wf1 = *(const short8*)(smem + LW1 + ((KS) * 5 + (CT1)) * 512 + lane * 8); \
    aA0 = MFMA(wf0, (BA), aA0);  aB0 = MFMA(wf0, (BB), aB0);               \
    aA1 = MFMA(wf1, (BA), aA1);  aB1 = MFMA(wf1, (BB), aB1);               \
  }
#define L1_TWO(CT0, CT1) {                                                 \
    floatx4 aA0 = Z4, aB0 = Z4, aA1 = Z4, aB1 = Z4;                        \
    L1_STEP(0, CT0, CT1, afA0, afB0)                                       \
    L1_STEP(1, CT0, CT1, afA1, afB1)                                       \
    L1_STEP(2, CT0, CT1, afA2, afB2)                                       \
    L1_STEP(3, CT0, CT1, afA3, afB3)                                       \
    L1_STEP(4, CT0, CT1, bfrag, bfrag)                                     \
    if (midxA == g) { H_STORE(l16, CT0, aA0); H_STORE(l16, CT1, aA1); }    \
    if (midxB == g) { H_STORE(16 + l16, CT0, aB0); H_STORE(16 + l16, CT1, aB1); } \
  }
#define L1_ONE_STEP(KS, CT, BA, BB) {                                      \
    short8 wf = *(const short8*)(smem + LW1 + ((KS) * 5 + (CT)) * 512 + lane * 8); \
    aA = MFMA(wf, (BA), aA);  aB = MFMA(wf, (BB), aB);                     \
  }
#define L1_ONE(CT) {                                                       \
    floatx4 aA = Z4, aB = Z4;                                              \
    L1_ONE_STEP(0, CT, afA0, afB0)                                         \
    L1_ONE_STEP(1, CT, afA1, afB1)                                         \
    L1_ONE_STEP(2, CT, afA2, afB2)                                         \
    L1_ONE_STEP(3, CT, afA3, afB3)                                         \
    L1_ONE_STEP(4, CT, bfrag, bfrag)                                       \
    if (midxA == g) H_STORE(l16, CT, aA);                                  \
    if (midxB == g) H_STORE(16 + l16, CT, aB);                             \
  }

// ---- h-frag loads (named; cols 80..95 carry 1.0-pad for bias-in-k) ----
#define LOAD_H()                                                           \
    short8 hA0 = *(const short8*)(hbuf + l16 * SH +  0 + quad * 8);        \
    short8 hA1 = *(const short8*)(hbuf + l16 * SH + 32 + quad * 8);        \
    short8 hA2 = *(const short8*)(hbuf + l16 * SH + 64 + quad * 8);        \
    short8 hB0 = *(const short8*)(hbuf + (16 + l16) * SH +  0 + quad * 8); \
    short8 hB1 = *(const short8*)(hbuf + (16 + l16) * SH + 32 + quad * 8); \
    short8 hB2 = *(const short8*)(hbuf + (16 + l16) * SH + 64 + quad * 8);

// ---- L2/L3: weights from global (WB, 15-chunk stride-5 layout) ----
#define L23_STEP(WB, KS, CT0, CT1, HA, HB) {                               \
    short8 wf0 = *(const short8*)((WB) + ((KS) * 5 + (CT0)) * 512 + lane * 8); \
    short8 wf1 = *(const short8*)((WB) + ((KS) * 5 + (CT1)) * 512 + lane * 8); \
    aA0 = MFMA(wf0, (HA), aA0);  aB0 = MFMA(wf0, (HB), aB0);               \
    aA1 = MFMA(wf1, (HA), aA1);  aB1 = MFMA(wf1, (HB), aB1);               \
  }
#define L23_TWO(WB, CT0, CT1) {                                            \
    floatx4 aA0 = Z4, aB0 = Z4, aA1 = Z4, aB1 = Z4;                        \
    L23_STEP(WB, 0, CT0, CT1, hA0, hB0)                                    \
    L23_STEP(WB, 1, CT0, CT1, hA1, hB1)                                    \
    L23_STEP(WB, 2, CT0, CT1, hA2, hB2)                                    \
    H_STORE(l16, CT0, aA0);      H_STORE(l16, CT1, aA1);                   \
    H_STORE(16 + l16, CT0, aB0); H_STORE(16 + l16, CT1, aB1);              \
  }
#define L23_ONE_STEP(WB, KS, CT, HA, HB) {                                 \
    short8 wf = *(const short8*)((WB) + ((KS) * 5 + (CT)) * 512 + lane * 8); \
    aA = MFMA(wf, (HA), aA);  aB = MFMA(wf, (HB), aB);                     \
  }
#define L23_ONE(WB, CT) {                                                  \
    floatx4 aA = Z4, aB = Z4;                                              \
    L23_ONE_STEP(WB, 0, CT, hA0, hB0)                                      \
    L23_ONE_STEP(WB, 1, CT, hA1, hB1)                                      \
    L23_ONE_STEP(WB, 2, CT, hA2, hB2)                                      \
    H_STORE(l16, CT, aA);                                                  \
    H_STORE(16 + l16, CT, aB);                                             \
  }

// ---- L4: W4 layout is 6 chunks/game, (ks*2 + ct) — not stride-5 ----
#define L4_STEP(WB, KS, HA, HB) {                                          \
    short8 wf0 = *(const short8*)((WB) + ((KS) * 2 + 0) * 512 + lane * 8); \
    short8 wf1 = *(const short8*)((WB) + ((KS) * 2 + 1) * 512 + lane * 8); \
    aA0 = MFMA(wf0, (HA), aA0);  aB0 = MFMA(wf0, (HB), aB0);               \
    aA1 = MFMA(wf1, (HA), aA1);  aB1 = MFMA(wf1, (HB), aB1);               \
  }

__global__ __launch_bounds__(THREADS, 4) void gym_fused(
    const float* __restrict__ state, const int* __restrict__ idx,
    const unsigned short* __restrict__ wsw, float* __restrict__ out)
{
  __shared__ __align__(16) unsigned short smem[LDS_SH];

  const int tid  = threadIdx.x;
  const int lane = tid & 63;
  const int wv   = tid >> 6;
  const int l16  = lane & 15;
  const int quad = lane >> 4;
  unsigned short* hbuf = smem + LHB + wv * (32 * SH);
  const size_t blk0 = (size_t)blockIdx.x * (SLAB * NSLAB);

  // ---- hbuf pad cols 80..95 for all 32 rows: col80 = 1.0 (bias-in-k), 81..95 = 0 ----
  {
    int row = lane >> 1, grp = lane & 1;          // 32 rows x 2 groups of 8 shorts
    short8 v = (short8){0, 0, 0, 0, 0, 0, 0, 0};
    if (grp == 0) v[0] = (short)0x3F80;           // bf16 1.0 at col 80
    *(short8*)(hbuf + row * SH + 80 + grp * 8) = v;
  }

  // ---- constant B-frag for L1's ks=4 bias chunk: 1.0 at k=128 (quad 0, j 0) ----
  short8 bfrag = (short8){0, 0, 0, 0, 0, 0, 0, 0};
  if (quad == 0) bfrag[0] = (short)0x3F80;

  // ---- initial game (covered by stage_game's barrier pair) ----
  int curr_g = idx[blk0];
  stage_game(curr_g, wsw, smem, tid);

  for (int it = 0; it < NSLAB; ++it) {
    const size_t slab0 = blk0 + (size_t)it * SLAB;
    const size_t trow  = slab0 + wv * 32;         // this wave's 32 rows (2 x 16 tiles)
    const int tg_lo = idx[slab0];
    const int tg_hi = idx[slab0 + SLAB - 1];      // idx sorted
    const int midxA = idx[trow + l16];            // tile-A lane row's game
    const int midxB = idx[trow + 16 + l16];       // tile-B lane row's game

    for (int g = tg_lo; g <= tg_hi; ++g) {        // block-uniform loop (slab range)
      if (g != curr_g) { stage_game(g, wsw, smem, tid); curr_g = g; }

      // ---- state B'-fragments INSIDE the g-loop: live range = L1 only (the R15 fix).
      //      g-loop is single-iteration except at rare game boundaries (L2-hot reload).
      const float* spA = state + (trow + l16) * DDIM + quad * 8;
      short8 afA0 = ldbf8(spA);
      short8 afA1 = ldbf8(spA + 32);
      short8 afA2 = ldbf8(spA + 64);
      short8 afA3 = ldbf8(spA + 96);
      const float* spB = spA + 16 * DDIM;
      short8 afB0 = ldbf8(spB);
      short8 afB1 = ldbf8(spB + 32);
      short8 afB2 = ldbf8(spB + 64);
      short8 afB3 = ldbf8(spB + 96);

      // ---- L1: ct-pair outer; each W1 read -> 2 MFMAs; 16 acc regs live ----
      L1_TWO(0, 1)
      L1_TWO(2, 3)
      L1_ONE(4)

      // ---- L2: both tiles, weights streamed from global (L1/L2-resident) ----
      {
        LOAD_H()
        const unsigned short* wb = wsw + W2SW;
        L23_TWO(wb, 0, 1)
        L23_TWO(wb, 2, 3)
        L23_ONE(wb, 4)
      }
      // ---- L3 ----
      {
        LOAD_H()
        const unsigned short* wb = wsw + W3SW;
        L23_TWO(wb, 0, 1)
        L23_TWO(wb, 2, 3)
        L23_ONE(wb, 4)
      }
      // ---- L4: both tiles share W4 chunk reads; packed float2 out stores ----
      {
        LOAD_H()
        const unsigned short* wb = wsw + W4SW + g * (6 * 512);
        floatx4 aA0 = Z4, aB0 = Z4, aA1 = Z4, aB1 = Z4;
        L4_STEP(wb, 0, hA0, hB0)
        L4_STEP(wb, 1, hA1, hB1)
        L4_STEP(wb, 2, hA2, hB2)
        if (midxA == g) {                          // n = ct*16 + quad*4 + r, valid n<18
          float* op = out + (trow + l16) * ADIM;
          *(floatx2*)(op + quad * 4)     = (floatx2){aA0[0], aA0[1]};
          *(floatx2*)(op + quad * 4 + 2) = (floatx2){aA0[2], aA0[3]};
          if (quad == 0)
            *(floatx2*)(op + 16) = (floatx2){aA1[0], aA1[1]};
        }
        if (midxB == g) {
          float* op = out + (trow + 16 + l16) * ADIM;
          *(floatx2*)(op + quad * 4)     = (floatx2){aB0[0], aB0[1]};
          *(floatx2*)(op + quad * 4 + 2) = (floatx2){aB0[2], aB0[3]};
          if (quad == 0)
            *(floatx2*)(op + 16) = (floatx2){aB1[0], aB1[1]};
        }
      }
    }
  }
}

extern "C" void kernel_launch(void* const* d_in, const int* in_sizes, int n_in,
                              void* d_out, int out_size, void* d_ws, size_t ws_size,
                              hipStream_t stream) {
  const float* state = (const float*)d_in[0];
  const int*   idx   = (const int*)d_in[1];
  const float* W1    = (const float*)d_in[2];
  const float* b1    = (const float*)d_in[3];
  const float* W2    = (const float*)d_in[4];
  const float* b2    = (const float*)d_in[5];
  const float* W3    = (const float*)d_in[6];
  const float* b3    = (const float*)d_in[7];
  const float* W4    = (const float*)d_in[8];
  const float* b4    = (const float*)d_in[9];
  float*       out   = (float*)d_out;
  unsigned short* wsw = (unsigned short*)d_ws;   // 284672 B used

  convert_weights<<<(WTOT + 255) / 256, 256, 0, stream>>>(W1, b1, W2, W3, W4, b2, b3, b4, wsw);
  gym_fused<<<GRID, THREADS, 0, stream>>>(state, idx, wsw, out);
}

// Round 6
// 251.642 us; speedup vs baseline: 1.3399x; 1.3399x over previous
//
#include <hip/hip_runtime.h>

// GymNetwork: routed MLP, B=262144, D=128 -> F=80 -> 80 -> 80 -> A=18, G=8 (idx sorted).
// f32 I/O, bf16 MFMA compute (threshold 6e-2 = 8*bf16_eps*max|ref|).
//
// R16: R12/R14/R15 all failed to move WRITE_SIZE (283MB) or VGPR_Count (64) -> the
// spill is structural: launch_bounds(512,4) caps 128 regs/wave on the unified file,
// split arch=64 + accum=64; the non-accumulator working set of the 32-row structure
// (~110 regs) cannot fit 64 arch regs no matter how the source is arranged.
// Decisive A/B: raise the budget -> __launch_bounds__(512, 2) = 256 regs/wave,
// 1 block/CU (2 waves/EU). Trade: half the latency-hiding for zero spill.
// Everything else identical to R15.

#define B_TOT   262144
#define DDIM    128
#define FDIM    80
#define ADIM    18
#define SH      104    // LDS stride (shorts) for h rows; 208B breaks pow2 bank stride
#define THREADS 512
#define SLAB    256    // rows per block-iteration (8 waves x 32)
#define NSLAB   2      // block rows = 512
#define GRID    (B_TOT / (SLAB * NSLAB))   // 512 blocks

// swizzled bf16 weight workspace in d_ws (shorts); 512-short (1KB) chunks, lane-major
#define W1SW    0                       // 200 chunks: (g*25 + ks*5 + ct); ks=4 = b1 col
#define W2SW    102400                  // 15 chunks: (ks*5+ct); k=80 holds b2, 81..95 zero
#define W3SW    110080                  // 15 chunks; k=80 holds b3
#define W4SW    117760                  // 48 chunks: (g*6+ks*2+ct); k=80 holds b4
#define NCHUNK  278
#define WTOT    (NCHUNK * 512)          // 142336 shorts = 284672 bytes

// LDS layout (shorts)
#define LW1     0                       // 25 chunks (current g) = 12800
#define LHB     12800                   // 8 waves x 32 x SH = 26624
#define LDS_SH  39424                   // 78848 B

typedef __attribute__((ext_vector_type(8))) short short8;
typedef __attribute__((ext_vector_type(2))) unsigned int uint2v;
typedef __attribute__((ext_vector_type(4))) float floatx4;
typedef __attribute__((ext_vector_type(2))) float floatx2;

static __device__ __forceinline__ unsigned short f2bf(float f) {
  union { float f; unsigned u; } v; v.f = f;
  unsigned r = v.u + 0x7fffu + ((v.u >> 16) & 1u);   // RNE
  return (unsigned short)(r >> 16);
}
// pack two f32 -> bf16x2 (lo | hi<<16), RNE
static __device__ __forceinline__ unsigned pk2(float a, float b) {
  union { float f; unsigned u; } x, y; x.f = a; y.f = b;
  unsigned ra = x.u + 0x7fffu + ((x.u >> 16) & 1u);
  unsigned rb = y.u + 0x7fffu + ((y.u >> 16) & 1u);
  return (ra >> 16) | (rb & 0xffff0000u);
}
// load 8 consecutive f32 -> one bf16x8 fragment (named-scalar friendly)
static __device__ __forceinline__ short8 ldbf8(const float* sp) {
  floatx4 va = *(const floatx4*)(sp);
  floatx4 vb = *(const floatx4*)(sp + 4);
  short8 f;
  unsigned u0 = pk2(va[0], va[1]), u1 = pk2(va[2], va[3]);
  unsigned u2 = pk2(vb[0], vb[1]), u3 = pk2(vb[2], vb[3]);
  f[0] = (short)(u0 & 0xffff); f[1] = (short)(u0 >> 16);
  f[2] = (short)(u1 & 0xffff); f[3] = (short)(u1 >> 16);
  f[4] = (short)(u2 & 0xffff); f[5] = (short)(u2 >> 16);
  f[6] = (short)(u3 & 0xffff); f[7] = (short)(u3 >> 16);
  return f;
}

// ---- prologue: f32 weights -> bf16 swizzled chunks; biases folded into extra-k cols ----
// chunk: ws[chunk*512 + lane*8 + j] = W[n = ct*16 + (lane&15)][k = ks*32 + (lane>>4)*8 + j]
__global__ void convert_weights(const float* __restrict__ W1, const float* __restrict__ b1,
                                const float* __restrict__ W2, const float* __restrict__ W3,
                                const float* __restrict__ W4, const float* __restrict__ b2,
                                const float* __restrict__ b3, const float* __restrict__ b4,
                                unsigned short* __restrict__ ws) {
  int t = blockIdx.x * 256 + threadIdx.x;
  if (t >= WTOT) return;
  int chunk = t >> 9, r = t & 511;
  int lane = r >> 3, j = r & 7;
  int l16 = lane & 15, quad = lane >> 4;
  float val;
  if (chunk < 200) {                              // W1: [G][80][128] + ks=4 bias col
    int g = chunk / 25, rem = chunk % 25, ks = rem / 5, ct = rem % 5;
    int n = ct * 16 + l16, k = ks * 32 + quad * 8 + j;
    val = (ks < 4) ? W1[(g * FDIM + n) * DDIM + k]
                   : ((quad == 0 && j == 0) ? b1[g * FDIM + n] : 0.f);
  } else if (chunk < 215) {                       // W2: 80x80 -> 80x96, k80 = b2[n]
    int c = chunk - 200, ks = c / 5, ct = c % 5;
    int n = ct * 16 + l16, k = ks * 32 + quad * 8 + j;
    val = (k < FDIM) ? W2[n * FDIM + k] : (k == FDIM ? b2[n] : 0.f);
  } else if (chunk < 230) {                       // W3, k80 = b3[n]
    int c = chunk - 215, ks = c / 5, ct = c % 5;
    int n = ct * 16 + l16, k = ks * 32 + quad * 8 + j;
    val = (k < FDIM) ? W3[n * FDIM + k] : (k == FDIM ? b3[n] : 0.f);
  } else {                                        // W4: Gx18x80 -> Gx32x96, k80 = b4[g][n]
    int c = chunk - 230, g = c / 6, rem = c % 6, ks = rem >> 1, ct = rem & 1;
    int n = ct * 16 + l16, k = ks * 32 + quad * 8 + j;
    val = (n < ADIM) ? ((k < FDIM) ? W4[(g * ADIM + n) * FDIM + k]
                                   : (k == FDIM ? b4[g * ADIM + n] : 0.f)) : 0.f;
  }
  ws[t] = f2bf(val);
}

// W1[g] (25 chunks incl. bias col) -> LDS; barrier pair; block-uniform call sites
static __device__ __forceinline__ void stage_game(
    int g, const unsigned short* __restrict__ wsw, unsigned short* smem, int tid)
{
  __syncthreads();                                // all waves done with old W1
  const short8* src = (const short8*)(wsw + W1SW + g * (25 * 512));
  short8* dst = (short8*)(smem + LW1);
#pragma unroll
  for (int i = 0; i < 4; ++i) {
    int t = i * THREADS + tid;
    if (t < 1600) dst[t] = src[t];
  }
  __syncthreads();                                // new W1 visible
}

#define Z4 ((floatx4){0.f, 0.f, 0.f, 0.f})
#define MFMA(a, b, c) __builtin_amdgcn_mfma_f32_16x16x32_bf16((a), (b), (c), 0, 0, 0)

// relu + pack + h-store of one ct's 4-float acc (row ROW of this wave's hbuf)
#define H_STORE(ROW, CT, ACC) {                                            \
    uint2v u_;                                                             \
    u_[0] = pk2(fmaxf((ACC)[0], 0.f), fmaxf((ACC)[1], 0.f));               \
    u_[1] = pk2(fmaxf((ACC)[2], 0.f), fmaxf((ACC)[3], 0.f));               \
    *(uint2v*)(hbuf + (ROW) * SH + (CT) * 16 + quad * 4) = u_;             \
  }

// ---- L1: W1 from LDS; hand-unrolled ks steps over NAMED b-frags ----
#define L1_STEP(KS, CT0, CT1, BA, BB) {                                    \
    short8 wf0 = *(const short8*)(smem + LW1 + ((KS) * 5 + (CT0)) * 512 + lane * 8); \
    short8 wf1 = *(const short8*)(smem + LW1 + ((KS) * 5 + (CT1)) * 512 + lane * 8); \
    aA0 = MFMA(wf0, (BA), aA0);  aB0 = MFMA(wf0, (BB), aB0);               \
    aA1 = MFMA(wf1, (BA), aA1);  aB1 = MFMA(wf1, (BB), aB1);               \
  }
#define L1_TWO(CT0, CT1) {                                                 \
    floatx4 aA0 = Z4, aB0 = Z4, aA1 = Z4, aB1 = Z4;                        \
    L1_STEP(0, CT0, CT1, afA0, afB0)                                       \
    L1_STEP(1, CT0, CT1, afA1, afB1)                                       \
    L1_STEP(2, CT0, CT1, afA2, afB2)                                       \
    L1_STEP(3, CT0, CT1, afA3, afB3)                                       \
    L1_STEP(4, CT0, CT1, bfrag, bfrag)                                     \
    if (midxA == g) { H_STORE(l16, CT0, aA0); H_STORE(l16, CT1, aA1); }    \
    if (midxB == g) { H_STORE(16 + l16, CT0, aB0); H_STORE(16 + l16, CT1, aB1); } \
  }
#define L1_ONE_STEP(KS, CT, BA, BB) {                                      \
    short8 wf = *(const short8*)(smem + LW1 + ((KS) * 5 + (CT)) * 512 + lane * 8); \
    aA = MFMA(wf, (BA), aA);  aB = MFMA(wf, (BB), aB);                     \
  }
#define L1_ONE(CT) {                                                       \
    floatx4 aA = Z4, aB = Z4;                                              \
    L1_ONE_STEP(0, CT, afA0, afB0)                                         \
    L1_ONE_STEP(1, CT, afA1, afB1)                                         \
    L1_ONE_STEP(2, CT, afA2, afB2)                                         \
    L1_ONE_STEP(3, CT, afA3, afB3)                                         \
    L1_ONE_STEP(4, CT, bfrag, bfrag)                                       \
    if (midxA == g) H_STORE(l16, CT, aA);                                  \
    if (midxB == g) H_STORE(16 + l16, CT, aB);                             \
  }

// ---- h-frag loads (named; cols 80..95 carry 1.0-pad for bias-in-k) ----
#define LOAD_H()                                                           \
    short8 hA0 = *(const short8*)(hbuf + l16 * SH +  0 + quad * 8);        \
    short8 hA1 = *(const short8*)(hbuf + l16 * SH + 32 + quad * 8);        \
    short8 hA2 = *(const short8*)(hbuf + l16 * SH + 64 + quad * 8);        \
    short8 hB0 = *(const short8*)(hbuf + (16 + l16) * SH +  0 + quad * 8); \
    short8 hB1 = *(const short8*)(hbuf + (16 + l16) * SH + 32 + quad * 8); \
    short8 hB2 = *(const short8*)(hbuf + (16 + l16) * SH + 64 + quad * 8);

// ---- L2/L3: weights from global (WB, 15-chunk stride-5 layout) ----
#define L23_STEP(WB, KS, CT0, CT1, HA, HB) {                               \
    short8 wf0 = *(const short8*)((WB) + ((KS) * 5 + (CT0)) * 512 + lane * 8); \
    short8 wf1 = *(const short8*)((WB) + ((KS) * 5 + (CT1)) * 512 + lane * 8); \
    aA0 = MFMA(wf0, (HA), aA0);  aB0 = MFMA(wf0, (HB), aB0);               \
    aA1 = MFMA(wf1, (HA), aA1);  aB1 = MFMA(wf1, (HB), aB1);               \
  }
#define L23_TWO(WB, CT0, CT1) {                                            \
    floatx4 aA0 = Z4, aB0 = Z4, aA1 = Z4, aB1 = Z4;                        \
    L23_STEP(WB, 0, CT0, CT1, hA0, hB0)                                    \
    L23_STEP(WB, 1, CT0, CT1, hA1, hB1)                                    \
    L23_STEP(WB, 2, CT0, CT1, hA2, hB2)                                    \
    H_STORE(l16, CT0, aA0);      H_STORE(l16, CT1, aA1);                   \
    H_STORE(16 + l16, CT0, aB0); H_STORE(16 + l16, CT1, aB1);              \
  }
#define L23_ONE_STEP(WB, KS, CT, HA, HB) {                                 \
    short8 wf = *(const short8*)((WB) + ((KS) * 5 + (CT)) * 512 + lane * 8); \
    aA = MFMA(wf, (HA), aA);  aB = MFMA(wf, (HB), aB);                     \
  }
#define L23_ONE(WB, CT) {                                                  \
    floatx4 aA = Z4, aB = Z4;                                              \
    L23_ONE_STEP(WB, 0, CT, hA0, hB0)                                      \
    L23_ONE_STEP(WB, 1, CT, hA1, hB1)                                      \
    L23_ONE_STEP(WB, 2, CT, hA2, hB2)                                      \
    H_STORE(l16, CT, aA);                                                  \
    H_STORE(16 + l16, CT, aB);                                             \
  }

// ---- L4: W4 layout is 6 chunks/game, (ks*2 + ct) — not stride-5 ----
#define L4_STEP(WB, KS, HA, HB) {                                          \
    short8 wf0 = *(const short8*)((WB) + ((KS) * 2 + 0) * 512 + lane * 8); \
    short8 wf1 = *(const short8*)((WB) + ((KS) * 2 + 1) * 512 + lane * 8); \
    aA0 = MFMA(wf0, (HA), aA0);  aB0 = MFMA(wf0, (HB), aB0);               \
    aA1 = MFMA(wf1, (HA), aA1);  aB1 = MFMA(wf1, (HB), aB1);               \
  }

__global__ __launch_bounds__(THREADS, 2) void gym_fused(
    const float* __restrict__ state, const int* __restrict__ idx,
    const unsigned short* __restrict__ wsw, float* __restrict__ out)
{
  __shared__ __align__(16) unsigned short smem[LDS_SH];

  const int tid  = threadIdx.x;
  const int lane = tid & 63;
  const int wv   = tid >> 6;
  const int l16  = lane & 15;
  const int quad = lane >> 4;
  unsigned short* hbuf = smem + LHB + wv * (32 * SH);
  const size_t blk0 = (size_t)blockIdx.x * (SLAB * NSLAB);

  // ---- hbuf pad cols 80..95 for all 32 rows: col80 = 1.0 (bias-in-k), 81..95 = 0 ----
  {
    int row = lane >> 1, grp = lane & 1;          // 32 rows x 2 groups of 8 shorts
    short8 v = (short8){0, 0, 0, 0, 0, 0, 0, 0};
    if (grp == 0) v[0] = (short)0x3F80;           // bf16 1.0 at col 80
    *(short8*)(hbuf + row * SH + 80 + grp * 8) = v;
  }

  // ---- constant B-frag for L1's ks=4 bias chunk: 1.0 at k=128 (quad 0, j 0) ----
  short8 bfrag = (short8){0, 0, 0, 0, 0, 0, 0, 0};
  if (quad == 0) bfrag[0] = (short)0x3F80;

  // ---- initial game (covered by stage_game's barrier pair) ----
  int curr_g = idx[blk0];
  stage_game(curr_g, wsw, smem, tid);

  for (int it = 0; it < NSLAB; ++it) {
    const size_t slab0 = blk0 + (size_t)it * SLAB;
    const size_t trow  = slab0 + wv * 32;         // this wave's 32 rows (2 x 16 tiles)
    const int tg_lo = idx[slab0];
    const int tg_hi = idx[slab0 + SLAB - 1];      // idx sorted
    const int midxA = idx[trow + l16];            // tile-A lane row's game
    const int midxB = idx[trow + 16 + l16];       // tile-B lane row's game

    for (int g = tg_lo; g <= tg_hi; ++g) {        // block-uniform loop (slab range)
      if (g != curr_g) { stage_game(g, wsw, smem, tid); curr_g = g; }

      // ---- state B'-fragments inside the g-loop (live range = L1 only) ----
      const float* spA = state + (trow + l16) * DDIM + quad * 8;
      short8 afA0 = ldbf8(spA);
      short8 afA1 = ldbf8(spA + 32);
      short8 afA2 = ldbf8(spA + 64);
      short8 afA3 = ldbf8(spA + 96);
      const float* spB = spA + 16 * DDIM;
      short8 afB0 = ldbf8(spB);
      short8 afB1 = ldbf8(spB + 32);
      short8 afB2 = ldbf8(spB + 64);
      short8 afB3 = ldbf8(spB + 96);

      // ---- L1: ct-pair outer; each W1 read -> 2 MFMAs ----
      L1_TWO(0, 1)
      L1_TWO(2, 3)
      L1_ONE(4)

      // ---- L2: both tiles, weights streamed from global (L1/L2-resident) ----
      {
        LOAD_H()
        const unsigned short* wb = wsw + W2SW;
        L23_TWO(wb, 0, 1)
        L23_TWO(wb, 2, 3)
        L23_ONE(wb, 4)
      }
      // ---- L3 ----
      {
        LOAD_H()
        const unsigned short* wb = wsw + W3SW;
        L23_TWO(wb, 0, 1)
        L23_TWO(wb, 2, 3)
        L23_ONE(wb, 4)
      }
      // ---- L4: both tiles share W4 chunk reads; packed float2 out stores ----
      {
        LOAD_H()
        const unsigned short* wb = wsw + W4SW + g * (6 * 512);
        floatx4 aA0 = Z4, aB0 = Z4, aA1 = Z4, aB1 = Z4;
        L4_STEP(wb, 0, hA0, hB0)
        L4_STEP(wb, 1, hA1, hB1)
        L4_STEP(wb, 2, hA2, hB2)
        if (midxA == g) {                          // n = ct*16 + quad*4 + r, valid n<18
          float* op = out + (trow + l16) * ADIM;
          *(floatx2*)(op + quad * 4)     = (floatx2){aA0[0], aA0[1]};
          *(floatx2*)(op + quad * 4 + 2) = (floatx2){aA0[2], aA0[3]};
          if (quad == 0)
            *(floatx2*)(op + 16) = (floatx2){aA1[0], aA1[1]};
        }
        if (midxB == g) {
          float* op = out + (trow + 16 + l16) * ADIM;
          *(floatx2*)(op + quad * 4)     = (floatx2){aB0[0], aB0[1]};
          *(floatx2*)(op + quad * 4 + 2) = (floatx2){aB0[2], aB0[3]};
          if (quad == 0)
            *(floatx2*)(op + 16) = (floatx2){aB1[0], aB1[1]};
        }
      }
    }
  }
}

extern "C" void kernel_launch(void* const* d_in, const int* in_sizes, int n_in,
                              void* d_out, int out_size, void* d_ws, size_t ws_size,
                              hipStream_t stream) {
  const float* state = (const float*)d_in[0];
  const int*   idx   = (const int*)d_in[1];
  const float* W1    = (const float*)d_in[2];
  const float* b1    = (const float*)d_in[3];
  const float* W2    = (const float*)d_in[4];
  const float* b2    = (const float*)d_in[5];
  const float* W3    = (const float*)d_in[6];
  const float* b3    = (const float*)d_in[7];
  const float* W4    = (const float*)d_in[8];
  const float* b4    = (const float*)d_in[9];
  float*       out   = (float*)d_out;
  unsigned short* wsw = (unsigned short*)d_ws;   // 284672 B used

  convert_weights<<<(WTOT + 255) / 256, 256, 0, stream>>>(W1, b1, W2, W3, W4, b2, b3, b4, wsw);
  gym_fused<<<GRID, THREADS, 0, stream>>>(state, idx, wsw, out);
}